// Round 3
// baseline (495.595 us; speedup 1.0000x reference)
//
#include <hip/hip_runtime.h>

// ---------------------------------------------------------------------------
// Fused 3x3 valid conv (64->128) + bias + *2 + min over oc.
// Implicit GEMM, mfma_f32_32x32x16_bf16.
// Block: 256 thr (4 waves), tile 16H x 16W x 128 oc. Wave: rows wv*4..wv*4+3
// as 2 M-tiles (M=32 = 2 rows x 16 cols) x 4 N-tiles (32 oc), acc 128 regs.
// K = 576 split as [2 ic-chunks of 32] x [3 kh groups] x [3 kw taps x 2 K=16].
// R5: B fragments read DIRECTLY from global (ws, 147 KB, L1/L2-resident by
// construction — 4096 blocks re-read it; per-phase working set 24.5 KB < L1).
// Rationale (R4 counters): the CU-shared DS pipe was the structural binder —
// 8 waves x 24 B-frag ds_read_b128 x 12cyc + wl staging writes = ~4600
// cyc/phase vs 3100 MFMA — and W-through-LDS forced a barrier+vmcnt drain
// every phase. Direct-global B: ws is repacked lane-ordered, so each frag is
// one coalesced global_load_dwordx4 (base + lane*16B, imm offsets). LDS now
// holds ONLY xs (20.7 KB); 3 barriers total (prologue + around stage_x(1)).
// Full unroll -> every subphase's 4 B-loads are SSA-fresh; the compiler
// software-pipelines them ahead of preceding MFMAs within the 256-reg budget
// (no per-phase barrier drains left to defeat it).
// R4 lessons kept: lane-ordered W fragments (conflict-free), x-staging plo
// interleave (4-way not 16-way write conflicts), slot-folding epilogue.
// R3 lesson kept: x staging px-major. R2 lesson kept: no big reg prefetch
// against the 128-reg acc tile (B in-flight regs are SSA/short-lived).
// LDS 20,736 B: xs [18 row][18 col][32 ic] bf16, octet swz o^((col>>1)&3)^(row&3)
// ---------------------------------------------------------------------------

#define XR 18
#define XC 18
#define XTILE_SH (XR * XC * 32)  // 10368 shorts = 20736 B

typedef __attribute__((ext_vector_type(8))) short short8;
typedef __attribute__((ext_vector_type(16))) float f32x16;
typedef __attribute__((ext_vector_type(4))) float f4;

__device__ __forceinline__ unsigned short f2bf(float f) {
  unsigned int u = __builtin_bit_cast(unsigned int, f);
  u += 0x7FFFu + ((u >> 16) & 1u);  // round-to-nearest-even
  return (unsigned short)(u >> 16);
}
__device__ __forceinline__ unsigned int pk2(float lo, float hi) {
  return (unsigned int)f2bf(lo) | ((unsigned int)f2bf(hi) << 16);
}

// x LDS put: (row, col, ic-pair) -> swizzled dword address.
__device__ __forceinline__ void xput(unsigned short* xs, int row, int col,
                                     int pair, unsigned int pk) {
  int o = ((pair >> 2) ^ ((col >> 1) & 3) ^ (row & 3));
  int off = ((row * XC + col) << 5) + (o << 3) + ((pair & 3) << 1);
  *(unsigned int*)&xs[off] = pk;
}

// W fp32 [oc][ic64][kh][kw] -> ws bf16 lane-ordered fragments:
// idx = ((((pg*3+tt)*2+ch)*4+n)*64+l)*8+e
// value = w[oc = n*32+(l&31)][ic = c*32+ch*16+(l>>5)*8+e][kh=g][kw=tt]
__global__ void repack_w(const float* __restrict__ w,
                         unsigned short* __restrict__ ws) {
  int idx = blockIdx.x * 256 + threadIdx.x;  // 73728 exact
  int e  = idx & 7;
  int l  = (idx >> 3) & 63;
  int n  = (idx >> 9) & 3;
  int ch = (idx >> 11) & 1;
  int rest = idx >> 12;  // 0..17 = pg*3 + tt
  int tt = rest % 3;
  int pg = rest / 3;
  int c = pg / 3, g = pg % 3;
  int oc = n * 32 + (l & 31);
  int ic = c * 32 + ch * 16 + (l >> 5) * 8 + e;
  ws[idx] = f2bf(w[oc * 576 + ic * 9 + g * 3 + tt]);
}

__global__ __launch_bounds__(256, 2) void conv_min_kernel(
    const float* __restrict__ x, const unsigned short* __restrict__ ws,
    const float* __restrict__ bias, float* __restrict__ out) {
  __shared__ unsigned short xs[XTILE_SH];

  const int tid  = threadIdx.x;
  const int wv   = tid >> 6;
  const int lane = tid & 63;
  const int cl   = lane & 15;
  const int ro   = (lane >> 4) & 1;
  const int hi   = lane >> 5;

  const int W0 = blockIdx.x * 16;
  const int H0 = blockIdx.y * 16;
  const int b  = blockIdx.z;
  const float* xb = x + (size_t)b * 64 * 65536;

  f32x16 acc[2][4];
#pragma unroll
  for (int mt = 0; mt < 2; ++mt)
#pragma unroll
    for (int n = 0; n < 4; ++n)
#pragma unroll
      for (int r = 0; r < 16; ++r) acc[mt][n][r] = 0.f;

  // ---- x ic-chunk stage, px-major (coalesced) ----
  // plo interleave: pair&3 varies within each wave -> write banks 4-way.
  auto stage_x = [&](int c) {
    for (int i = tid; i < 1152; i += 256) {
      int g4   = i & 3;
      int plo  = (i >> 2) & 3;
      int q    = i >> 4;            // 0..71
      int row  = q % 18;
      int phi  = q / 18;            // 0..3
      int pair = phi * 4 + plo;
      int gr = min(H0 + row, 255);  // clamped rows feed only discarded oh
      const float* p =
          xb + (size_t)(c * 32 + pair * 2) * 65536 + gr * 256 + W0 + g4 * 4;
      f4 a = *(const f4*)p;
      f4 d = *(const f4*)(p + 65536);
#pragma unroll
      for (int e = 0; e < 4; ++e)
        xput(xs, row, g4 * 4 + e, pair, pk2(a[e], d[e]));
    }
    // Ragged cols 16,17 (col-clamped: feeds only ow >= 254, never stored).
    for (int i = tid; i < 288; i += 256) {
      int row = i % 18, pair = i / 18;
      int gr = min(H0 + row, 255);
      int gc = min(W0 + 16, 254);
      const float* p =
          xb + (size_t)(c * 32 + pair * 2) * 65536 + gr * 256 + gc;
      float2 a = *(const float2*)p;
      float2 d = *(const float2*)(p + 65536);
      xput(xs, row, 16, pair, pk2(a.x, d.x));
      xput(xs, row, 17, pair, pk2(a.y, d.y));
    }
  };

  // ---- prologue ----
  stage_x(0);
  __syncthreads();

  // Per-lane W base: fragment sp-block = 2048 shorts, n-frag = 512 shorts.
  const unsigned short* wlane = ws + (lane << 3);

#pragma unroll
  for (int pg = 0; pg < 6; ++pg) {
    const int g = pg % 3;
    if (pg == 3) {
      __syncthreads();  // all waves done reading xs(c=0)
      stage_x(1);
      __syncthreads();
    }
#pragma unroll
    for (int tt = 0; tt < 3; ++tt) {
#pragma unroll
      for (int ch = 0; ch < 2; ++ch) {
        const int sp = pg * 6 + tt * 2 + ch;  // 0..35, compile-time
        const unsigned short* wp = wlane + sp * 2048;
        short8 bf0 = *(const short8*)(wp);
        short8 bf1 = *(const short8*)(wp + 512);
        short8 bf2 = *(const short8*)(wp + 1024);
        short8 bf3 = *(const short8*)(wp + 1536);
        __builtin_amdgcn_s_setprio(1);
#pragma unroll
        for (int mt = 0; mt < 2; ++mt) {
          int rowx = wv * 4 + mt * 2 + ro + g;
          int colx = cl + tt;
          int o    = ch * 2 + hi;  // ic octet
          short8 af = *(const short8*)&xs[((rowx * XC + colx) << 5) +
                                          ((o ^ ((colx >> 1) & 3) ^
                                            (rowx & 3)) << 3)];
          acc[mt][0] = __builtin_amdgcn_mfma_f32_32x32x16_bf16(
              af, bf0, acc[mt][0], 0, 0, 0);
          acc[mt][1] = __builtin_amdgcn_mfma_f32_32x32x16_bf16(
              af, bf1, acc[mt][1], 0, 0, 0);
          acc[mt][2] = __builtin_amdgcn_mfma_f32_32x32x16_bf16(
              af, bf2, acc[mt][2], 0, 0, 0);
          acc[mt][3] = __builtin_amdgcn_mfma_f32_32x32x16_bf16(
              af, bf3, acc[mt][3], 0, 0, 0);
        }
        __builtin_amdgcn_s_setprio(0);
      }
    }
  }

  // ---- epilogue: min over 128 oc of (acc + bias), then *2, store ----
  // Slot-folding butterfly: lane ends holding slot r = lane&15; xor16
  // completes the 32-lane (oc) reduce. 32 shfl/wave.
  float bv[4];
#pragma unroll
  for (int n = 0; n < 4; ++n) bv[n] = bias[n * 32 + (lane & 31)];

#pragma unroll
  for (int mt = 0; mt < 2; ++mt) {
    float v[16];
#pragma unroll
    for (int r = 0; r < 16; ++r) {
      float t0 = fminf(acc[mt][0][r] + bv[0], acc[mt][1][r] + bv[1]);
      float t1 = fminf(acc[mt][2][r] + bv[2], acc[mt][3][r] + bv[3]);
      v[r] = fminf(t0, t1);
    }
    float w8[8], w4[4], w2[2], w1;
#pragma unroll
    for (int j = 0; j < 8; ++j) {
      int s = lane & 1;
      float xk = s ? v[2 * j + 1] : v[2 * j];
      float zk = s ? v[2 * j] : v[2 * j + 1];
      w8[j] = fminf(xk, __shfl_xor(zk, 1));
    }
#pragma unroll
    for (int j = 0; j < 4; ++j) {
      int s = (lane >> 1) & 1;
      float xk = s ? w8[2 * j + 1] : w8[2 * j];
      float zk = s ? w8[2 * j] : w8[2 * j + 1];
      w4[j] = fminf(xk, __shfl_xor(zk, 2));
    }
#pragma unroll
    for (int j = 0; j < 2; ++j) {
      int s = (lane >> 2) & 1;
      float xk = s ? w4[2 * j + 1] : w4[2 * j];
      float zk = s ? w4[2 * j] : w4[2 * j + 1];
      w2[j] = fminf(xk, __shfl_xor(zk, 4));
    }
    {
      int s = (lane >> 3) & 1;
      float xk = s ? w2[1] : w2[0];
      float zk = s ? w2[0] : w2[1];
      w1 = fminf(xk, __shfl_xor(zk, 8));
    }
    w1 = fminf(w1, __shfl_xor(w1, 16));
    // lane holds slot r = lane&15; C/D map: m = (r&3) + 8*(r>>2) + 4*hi
    int r  = lane & 15;
    int m  = (r & 3) + 8 * (r >> 2) + 4 * hi;
    int oh = H0 + wv * 4 + mt * 2 + (m >> 4);
    int ow = W0 + (m & 15);
    if ((lane & 16) == 0 && oh < 254 && ow < 254)
      out[((size_t)b * 254 + oh) * 254 + ow] = w1 * 2.0f;
  }
}

extern "C" void kernel_launch(void* const* d_in, const int* in_sizes, int n_in,
                              void* d_out, int out_size, void* d_ws,
                              size_t ws_size, hipStream_t stream) {
  const float* x    = (const float*)d_in[0];
  const float* w    = (const float*)d_in[1];
  const float* bias = (const float*)d_in[2];
  float* out        = (float*)d_out;
  unsigned short* ws = (unsigned short*)d_ws;  // 147,456 B bf16 weights

  // ws re-poisoned before every call -> repack every call (same work/call).
  repack_w<<<288, 256, 0, stream>>>(w, ws);

  dim3 grid(16, 16, 16);  // 16x16 tiles over 254x254, batch 16
  conv_min_kernel<<<grid, 256, 0, stream>>>(x, ws, bias, out);
}